// Round 1
// baseline (98.006 us; speedup 1.0000x reference)
//
#include <hip/hip_runtime.h>

#define BATCH 64
#define L0 16384
#define L1 8192
#define NPG 4096         // nodes per graph after 2x pooling
#define CF 8
#define H 64
#define CHUNK 128
#define NCHUNK (NPG / CHUNK)   // 32

__device__ __forceinline__ float disv(int p) {
    // deg^-1/2 for chain+self-loop graph of NPG nodes; 0 outside the graph
    if (p < 0 || p >= NPG) return 0.f;
    if (p == 0 || p == NPG - 1) return 0.70710678118654752f;  // 1/sqrt(2)
    return 0.57735026918962576f;                              // 1/sqrt(3)
}

// conv1 (1->8, K=3, pad=1) + ReLU + maxpool2  -> t1[b][l][c]
__global__ __launch_bounds__(256) void k_conv1(const float* __restrict__ x,
        const float* __restrict__ w, const float* __restrict__ bias,
        float* __restrict__ t1) {
    int idx = blockIdx.x * 256 + threadIdx.x;   // b*L1 + l
    int b = idx >> 13;
    int l = idx & (L1 - 1);
    const float* xb = x + (size_t)b * L0;
    int p = 2 * l;
    float v0 = (p - 1 >= 0) ? xb[p - 1] : 0.f;
    float v1 = xb[p];
    float v2 = xb[p + 1];
    float v3 = (p + 2 < L0) ? xb[p + 2] : 0.f;
    float out[CF];
    #pragma unroll
    for (int c = 0; c < CF; ++c) {
        float w0 = w[c * 3 + 0], w1 = w[c * 3 + 1], w2 = w[c * 3 + 2];
        float bb = bias[c];
        float y0 = bb + w0 * v0 + w1 * v1 + w2 * v2;
        float y1 = bb + w0 * v1 + w1 * v2 + w2 * v3;
        out[c] = fmaxf(fmaxf(y0, y1), 0.f);
    }
    float4* dst = (float4*)(t1 + (size_t)idx * CF);
    dst[0] = make_float4(out[0], out[1], out[2], out[3]);
    dst[1] = make_float4(out[4], out[5], out[6], out[7]);
}

// conv2 (8->8, K=3, pad=1) + ReLU + maxpool2 -> nodes[b][l][c]
__global__ __launch_bounds__(256) void k_conv2(const float* __restrict__ t1,
        const float* __restrict__ w, const float* __restrict__ bias,
        float* __restrict__ nodes) {
    int idx = blockIdx.x * 256 + threadIdx.x;   // b*NPG + l
    int b = idx >> 12;
    int l = idx & (NPG - 1);
    const float* tb = t1 + (size_t)b * L1 * CF;
    float in_[4][CF];
    #pragma unroll
    for (int d = 0; d < 4; ++d) {
        int p = 2 * l - 1 + d;
        if (p >= 0 && p < L1) {
            const float4* s = (const float4*)(tb + (size_t)p * CF);
            float4 a = s[0], c = s[1];
            in_[d][0] = a.x; in_[d][1] = a.y; in_[d][2] = a.z; in_[d][3] = a.w;
            in_[d][4] = c.x; in_[d][5] = c.y; in_[d][6] = c.z; in_[d][7] = c.w;
        } else {
            #pragma unroll
            for (int ci = 0; ci < CF; ++ci) in_[d][ci] = 0.f;
        }
    }
    float out[CF];
    #pragma unroll
    for (int co = 0; co < CF; ++co) {
        float y0 = bias[co], y1 = bias[co];
        #pragma unroll
        for (int k = 0; k < 3; ++k) {
            #pragma unroll
            for (int ci = 0; ci < CF; ++ci) {
                float wv = w[(co * CF + ci) * 3 + k];
                y0 += wv * in_[k][ci];
                y1 += wv * in_[k + 1][ci];
            }
        }
        out[co] = fmaxf(fmaxf(y0, y1), 0.f);
    }
    float4* dst = (float4*)(nodes + (size_t)idx * CF);
    dst[0] = make_float4(out[0], out[1], out[2], out[3]);
    dst[1] = make_float4(out[4], out[5], out[6], out[7]);
}

// Fused GCN1 + GCN2 + ReLU + partial mean-pool.
// Block = one 128-node chunk of one graph. 256 threads = 4 waves.
// GCN1: s = stencil(nodes) (8-dim), h1 = relu(s@W1 + b1)
// GCN2: g = h1@W2 (pointwise in node index), h2 = relu(stencil(g) + b2)
__global__ __launch_bounds__(256) void k_gcn(const float* __restrict__ nodes,
        const float* __restrict__ w1, const float* __restrict__ b1,
        const float* __restrict__ w2, const float* __restrict__ b2,
        float* __restrict__ partials) {
    __shared__ float nodes_lds[CHUNK + 4][CF];   // rows s-2 .. s+129
    __shared__ float w1_lds[CF * H];
    __shared__ float b1_lds[H];
    __shared__ float b2_lds[H];
    __shared__ float scratch[4][H];              // per-wave h1 row
    __shared__ float g_lds[CHUNK + 2][H];        // rows s-1 .. s+128
    __shared__ float wred[4][H];

    int tid = threadIdx.x;
    int blk = blockIdx.x;            // b*NCHUNK + chunk
    int b = blk >> 5;
    int ch = blk & (NCHUNK - 1);
    int s = ch * CHUNK;
    int wave = tid >> 6;
    int j = tid & 63;

    // stage nodes chunk + halo(2), W1, biases
    const float* nb = nodes + (size_t)b * NPG * CF;
    for (int idx = tid; idx < (CHUNK + 4) * CF; idx += 256) {
        int r = idx >> 3, k = idx & 7;
        int p = s - 2 + r;
        nodes_lds[r][k] = (p >= 0 && p < NPG) ? nb[p * CF + k] : 0.f;
    }
    for (int idx = tid; idx < CF * H; idx += 256) w1_lds[idx] = w1[idx];
    if (tid < H) { b1_lds[tid] = b1[tid]; b2_lds[tid] = b2[tid]; }

    // each lane holds one W2 column (all blocks read same 16KB -> L2-resident)
    float w2col[H];
    #pragma unroll
    for (int k = 0; k < H; ++k) w2col[k] = w2[k * H + j];

    __syncthreads();

    // h1 then g = h1@W2, rows s-1 .. s+CHUNK (130 rows), round-robin by wave
    for (int r = wave; r < CHUNK + 2; r += 4) {
        int p = s - 1 + r;
        float dc = disv(p), dl = disv(p - 1), dr = disv(p + 1);
        float sst[CF];
        #pragma unroll
        for (int k = 0; k < CF; ++k) {
            sst[k] = dc * (dc * nodes_lds[r + 1][k] + dl * nodes_lds[r][k]
                           + dr * nodes_lds[r + 2][k]);
        }
        float h = b1_lds[j];
        #pragma unroll
        for (int k = 0; k < CF; ++k) h += sst[k] * w1_lds[k * H + j];
        h = fmaxf(h, 0.f);
        scratch[wave][j] = h;   // wave-internal round trip; no barrier needed
        float acc = 0.f;
        const float4* sr = (const float4*)scratch[wave];
        #pragma unroll
        for (int k4 = 0; k4 < H / 4; ++k4) {
            float4 v = sr[k4];
            acc += v.x * w2col[k4 * 4 + 0];
            acc += v.y * w2col[k4 * 4 + 1];
            acc += v.z * w2col[k4 * 4 + 2];
            acc += v.w * w2col[k4 * 4 + 3];
        }
        g_lds[r][j] = acc;
    }
    __syncthreads();

    // stencil on g + bias + relu, accumulate mean-pool partials
    float accj = 0.f;
    for (int r = 1 + wave; r < CHUNK + 1; r += 4) {
        int p = s - 1 + r;
        float dc = disv(p), dl = disv(p - 1), dr = disv(p + 1);
        float t = dc * (dc * g_lds[r][j] + dl * g_lds[r - 1][j]
                        + dr * g_lds[r + 1][j]);
        accj += fmaxf(t + b2_lds[j], 0.f);
    }
    wred[wave][j] = accj;
    __syncthreads();
    if (tid < H) {
        float sum = wred[0][tid] + wred[1][tid] + wred[2][tid] + wred[3][tid];
        partials[(size_t)blk * H + tid] = sum;
    }
}

// per-graph reduce over chunks + mean + fc
__global__ __launch_bounds__(64) void k_final(const float* __restrict__ partials,
        const float* __restrict__ fcw, const float* __restrict__ fcb,
        float* __restrict__ out) {
    __shared__ float pool_l[H];
    int b = blockIdx.x, j = threadIdx.x;
    float acc = 0.f;
    for (int c = 0; c < NCHUNK; ++c)
        acc += partials[((size_t)b * NCHUNK + c) * H + j];
    pool_l[j] = acc * (1.f / NPG);
    __syncthreads();
    if (j < 2) {
        float o = fcb[j];
        for (int k = 0; k < H; ++k) o += pool_l[k] * fcw[k * 2 + j];
        out[b * 2 + j] = o;
    }
}

extern "C" void kernel_launch(void* const* d_in, const int* in_sizes, int n_in,
                              void* d_out, int out_size, void* d_ws, size_t ws_size,
                              hipStream_t stream) {
    (void)in_sizes; (void)n_in; (void)out_size; (void)ws_size;
    const float* x   = (const float*)d_in[0];
    // d_in[1] = batch_size (hardcoded 64)
    const float* c1w = (const float*)d_in[2];
    const float* c1b = (const float*)d_in[3];
    const float* c2w = (const float*)d_in[4];
    const float* c2b = (const float*)d_in[5];
    const float* g1w = (const float*)d_in[6];
    const float* g1b = (const float*)d_in[7];
    const float* g2w = (const float*)d_in[8];
    const float* g2b = (const float*)d_in[9];
    const float* fcw = (const float*)d_in[10];
    const float* fcb = (const float*)d_in[11];
    float* out = (float*)d_out;

    float* t1       = (float*)d_ws;                       // [64][8192][8] = 16 MB
    float* nodes    = t1 + (size_t)BATCH * L1 * CF;       // [64][4096][8] = 8 MB
    float* partials = nodes + (size_t)BATCH * NPG * CF;   // [64][32][64]  = 0.5 MB

    k_conv1<<<BATCH * L1 / 256, 256, 0, stream>>>(x, c1w, c1b, t1);
    k_conv2<<<BATCH * NPG / 256, 256, 0, stream>>>(t1, c2w, c2b, nodes);
    k_gcn<<<BATCH * NCHUNK, 256, 0, stream>>>(nodes, g1w, g1b, g2w, g2b, partials);
    k_final<<<BATCH, 64, 0, stream>>>(partials, fcw, fcb, out);
}

// Round 2
// 45.082 us; speedup vs baseline: 2.1740x; 2.1740x over previous
//
#include <hip/hip_runtime.h>

typedef __attribute__((ext_vector_type(8))) short short8_t;
typedef __attribute__((ext_vector_type(4))) float f32x4;

#define BATCH 64
#define L0 16384
#define L1 8192
#define NPG 4096         // nodes per graph after 2x pooling
#define CF 8
#define H 64
#define CHUNK 128
#define NCHUNK 32                        // chunks per graph
#define NCHUNKS_TOTAL (BATCH * NCHUNK)   // 2048
#define GCN_BLOCKS 1024
#define CHUNKS_PER_BLOCK 2

__device__ __forceinline__ float disv(int p) {
    // deg^-1/2 for chain+self-loop graph of NPG nodes; 0 outside the graph
    if (p < 0 || p >= NPG) return 0.f;
    if (p == 0 || p == NPG - 1) return 0.70710678118654752f;  // 1/sqrt(2)
    return 0.57735026918962576f;                              // 1/sqrt(3)
}

__device__ __forceinline__ unsigned short f2bf(float f) {
    unsigned u = __float_as_uint(f);
    u += 0x7FFFu + ((u >> 16) & 1u);     // RNE
    return (unsigned short)(u >> 16);
}

// conv1 (1->8, K=3, pad=1) + ReLU + maxpool2 -> t1[b][l][c]
// extra block (blockIdx == 2048) builds bf16 MFMA B-fragments for W1/W2
__global__ __launch_bounds__(256) void k_conv1(const float* __restrict__ x,
        const float* __restrict__ w, const float* __restrict__ bias,
        float* __restrict__ t1,
        const float* __restrict__ w1, const float* __restrict__ w2,
        unsigned short* __restrict__ w1f, unsigned short* __restrict__ w2f) {
    int tid = threadIdx.x;
    if (blockIdx.x == BATCH * L1 / 256) {
        // B-frag layout for mfma_f32_16x16x32_bf16: lane holds B[k][n] with
        // n = lane&15, k = (lane>>4)*8 + i (i = 0..7)
        for (int e = tid; e < 4096; e += 256) {          // w2f[ct][ks][lane][i]
            int i = e & 7, lane = (e >> 3) & 63, ks = (e >> 9) & 1, ct = e >> 10;
            int k = ks * 32 + (lane >> 4) * 8 + i;
            int n = ct * 16 + (lane & 15);
            w2f[e] = f2bf(w2[k * H + n]);
        }
        for (int e = tid; e < 2048; e += 256) {          // w1f[ct][lane][i]
            int i = e & 7, lane = (e >> 3) & 63, ct = e >> 9;
            int k = (lane >> 4) * 8 + i;
            int n = ct * 16 + (lane & 15);
            w1f[e] = (k < CF) ? f2bf(w1[k * H + n]) : (unsigned short)0;
        }
        return;
    }
    int idx = blockIdx.x * 256 + tid;   // b*L1 + l
    int b = idx >> 13;
    int l = idx & (L1 - 1);
    const float* xb = x + (size_t)b * L0;
    int p = 2 * l;
    float v0 = (p - 1 >= 0) ? xb[p - 1] : 0.f;
    float v1 = xb[p];
    float v2 = xb[p + 1];
    float v3 = (p + 2 < L0) ? xb[p + 2] : 0.f;
    float out[CF];
    #pragma unroll
    for (int c = 0; c < CF; ++c) {
        float w0 = w[c * 3 + 0], w1c = w[c * 3 + 1], w2c = w[c * 3 + 2];
        float bb = bias[c];
        float y0 = bb + w0 * v0 + w1c * v1 + w2c * v2;
        float y1 = bb + w0 * v1 + w1c * v2 + w2c * v3;
        out[c] = fmaxf(fmaxf(y0, y1), 0.f);
    }
    float4* dst = (float4*)(t1 + (size_t)idx * CF);
    dst[0] = make_float4(out[0], out[1], out[2], out[3]);
    dst[1] = make_float4(out[4], out[5], out[6], out[7]);
}

// conv2 (8->8, K=3, pad=1) + ReLU + maxpool2 -> nodes[b][l][c]
__global__ __launch_bounds__(256) void k_conv2(const float* __restrict__ t1,
        const float* __restrict__ w, const float* __restrict__ bias,
        float* __restrict__ nodes) {
    int idx = blockIdx.x * 256 + threadIdx.x;   // b*NPG + l
    int b = idx >> 12;
    int l = idx & (NPG - 1);
    const float* tb = t1 + (size_t)b * L1 * CF;
    float in_[4][CF];
    #pragma unroll
    for (int d = 0; d < 4; ++d) {
        int p = 2 * l - 1 + d;
        if (p >= 0 && p < L1) {
            const float4* s = (const float4*)(tb + (size_t)p * CF);
            float4 a = s[0], c = s[1];
            in_[d][0] = a.x; in_[d][1] = a.y; in_[d][2] = a.z; in_[d][3] = a.w;
            in_[d][4] = c.x; in_[d][5] = c.y; in_[d][6] = c.z; in_[d][7] = c.w;
        } else {
            #pragma unroll
            for (int ci = 0; ci < CF; ++ci) in_[d][ci] = 0.f;
        }
    }
    float out[CF];
    #pragma unroll
    for (int co = 0; co < CF; ++co) {
        float y0 = bias[co], y1 = bias[co];
        #pragma unroll
        for (int k = 0; k < 3; ++k) {
            #pragma unroll
            for (int ci = 0; ci < CF; ++ci) {
                float wv = w[(co * CF + ci) * 3 + k];
                y0 += wv * in_[k][ci];
                y1 += wv * in_[k + 1][ci];
            }
        }
        out[co] = fmaxf(fmaxf(y0, y1), 0.f);
    }
    float4* dst = (float4*)(nodes + (size_t)idx * CF);
    dst[0] = make_float4(out[0], out[1], out[2], out[3]);
    dst[1] = make_float4(out[4], out[5], out[6], out[7]);
}

// Fused GCN1 + GCN2 + ReLU + mean-pool partials, MFMA-based.
// h2 = relu(stencil(relu(stencil(nodes)@W1 + b1))@W2 + b2); pool in regs.
// Persistent: GCN_BLOCKS blocks x CHUNKS_PER_BLOCK chunks of 128 nodes.
__global__ __launch_bounds__(256) void k_gcn(const float* __restrict__ nodes,
        const unsigned short* __restrict__ w1f, const unsigned short* __restrict__ w2f,
        const float* __restrict__ b1, const float* __restrict__ b2,
        float* __restrict__ partials) {
    __shared__ __align__(16) float nodes_lds[132][8];          // p = s-2 .. s+129
    __shared__ __align__(16) unsigned short sstA_lds[144][8];  // bf16, row r <-> p = s-1+r
    __shared__ __align__(16) float h1_lds[144][68];            // f32, row r <-> p = s-1+r
    __shared__ float red[4][64];

    int tid = threadIdx.x;
    int wave = tid >> 6;
    int l = tid & 63;
    int m = l & 15, q = l >> 4;

    const short8_t* w1v = (const short8_t*)w1f;
    const short8_t* w2v = (const short8_t*)w2f;
    short8_t w1fr[4], w2fr[4][2];
    float b1v[4], b2v[4];
    #pragma unroll
    for (int ct = 0; ct < 4; ++ct) {
        w1fr[ct]    = w1v[ct * 64 + l];
        w2fr[ct][0] = w2v[(ct * 2 + 0) * 64 + l];
        w2fr[ct][1] = w2v[(ct * 2 + 1) * 64 + l];
        b1v[ct] = b1[ct * 16 + m];
        b2v[ct] = b2[ct * 16 + m];
    }
    const f32x4 z4 = {0.f, 0.f, 0.f, 0.f};

    for (int it = 0; it < CHUNKS_PER_BLOCK; ++it) {
        int chunk = blockIdx.x + it * GCN_BLOCKS;
        int b = chunk >> 5, ch = chunk & 31;
        int s = ch * CHUNK;
        const float* nb = nodes + (size_t)b * NPG * CF;

        // stage nodes chunk + halo(2)
        for (int v = tid; v < 264; v += 256) {
            int n = v >> 1, half = v & 1;
            int p = s - 2 + n;
            float4 val = make_float4(0.f, 0.f, 0.f, 0.f);
            if (p >= 0 && p < NPG) val = *(const float4*)&nb[(size_t)p * CF + half * 4];
            *(float4*)&nodes_lds[n][half * 4] = val;
        }
        __syncthreads();

        // pre-stenciled GCN1 input, bf16
        for (int v = tid; v < 144 * 8; v += 256) {
            int r = v >> 3, c = v & 7;
            float out = 0.f;
            if (r < 130) {
                int p = s - 1 + r;
                float dc = disv(p), dl = disv(p - 1), dr = disv(p + 1);
                out = dc * (dc * nodes_lds[r + 1][c] + dl * nodes_lds[r][c]
                            + dr * nodes_lds[r + 2][c]);
            }
            sstA_lds[r][c] = f2bf(out);
        }
        __syncthreads();

        // GCN1: h1 rows 0..143 (>=130 garbage, never read), 9 rowtiles
        for (int rt = wave; rt < 9; rt += 4) {
            // A-frag: row m = l&15; k>=8 contents irrelevant (B rows zero)
            short8_t a = *(const short8_t*)&sstA_lds[rt * 16 + m][0];
            #pragma unroll
            for (int ct = 0; ct < 4; ++ct) {
                f32x4 c = __builtin_amdgcn_mfma_f32_16x16x32_bf16(a, w1fr[ct], z4, 0, 0, 0);
                #pragma unroll
                for (int i = 0; i < 4; ++i) {
                    h1_lds[rt * 16 + q * 4 + i][ct * 16 + m] =
                        fmaxf(c[i] + b1v[ct], 0.f);
                }
            }
        }
        __syncthreads();

        // GCN2: A2 = stencil(h1) as bf16 frags; pool in registers
        float pool_acc[4] = {0.f, 0.f, 0.f, 0.f};
        for (int rt = wave; rt < 8; rt += 4) {
            f32x4 accg[4] = {z4, z4, z4, z4};
            int r0 = rt * 16 + m;        // h1 row of p-1
            int p = s + r0;              // output node
            float dcp = disv(p), dlp = disv(p - 1), drp = disv(p + 1);
            float cl = dcp * dlp, cm = dcp * dcp, cr = dcp * drp;
            #pragma unroll
            for (int ks = 0; ks < 2; ++ks) {
                int koff = ks * 32 + q * 8;
                float4 lo0 = *(const float4*)&h1_lds[r0][koff];
                float4 lo1 = *(const float4*)&h1_lds[r0][koff + 4];
                float4 mi0 = *(const float4*)&h1_lds[r0 + 1][koff];
                float4 mi1 = *(const float4*)&h1_lds[r0 + 1][koff + 4];
                float4 hi0 = *(const float4*)&h1_lds[r0 + 2][koff];
                float4 hi1 = *(const float4*)&h1_lds[r0 + 2][koff + 4];
                short8_t a2;
                a2[0] = (short)f2bf(cm * mi0.x + cl * lo0.x + cr * hi0.x);
                a2[1] = (short)f2bf(cm * mi0.y + cl * lo0.y + cr * hi0.y);
                a2[2] = (short)f2bf(cm * mi0.z + cl * lo0.z + cr * hi0.z);
                a2[3] = (short)f2bf(cm * mi0.w + cl * lo0.w + cr * hi0.w);
                a2[4] = (short)f2bf(cm * mi1.x + cl * lo1.x + cr * hi1.x);
                a2[5] = (short)f2bf(cm * mi1.y + cl * lo1.y + cr * hi1.y);
                a2[6] = (short)f2bf(cm * mi1.z + cl * lo1.z + cr * hi1.z);
                a2[7] = (short)f2bf(cm * mi1.w + cl * lo1.w + cr * hi1.w);
                #pragma unroll
                for (int ct = 0; ct < 4; ++ct)
                    accg[ct] = __builtin_amdgcn_mfma_f32_16x16x32_bf16(
                        a2, w2fr[ct][ks], accg[ct], 0, 0, 0);
            }
            #pragma unroll
            for (int ct = 0; ct < 4; ++ct)
                #pragma unroll
                for (int i = 0; i < 4; ++i)
                    pool_acc[ct] += fmaxf(accg[ct][i] + b2v[ct], 0.f);
        }

        // reduce over the 4 q-groups, then over waves
        #pragma unroll
        for (int ct = 0; ct < 4; ++ct) {
            float v = pool_acc[ct];
            v += __shfl_xor(v, 16);
            v += __shfl_xor(v, 32);
            if (q == 0) red[wave][ct * 16 + m] = v;
        }
        __syncthreads();
        if (tid < 64) {
            partials[(size_t)chunk * H + tid] =
                red[0][tid] + red[1][tid] + red[2][tid] + red[3][tid];
        }
        __syncthreads();
    }
}

// per-graph reduce over chunks + mean + fc
__global__ __launch_bounds__(64) void k_final(const float* __restrict__ partials,
        const float* __restrict__ fcw, const float* __restrict__ fcb,
        float* __restrict__ out) {
    __shared__ float pool_l[H];
    int b = blockIdx.x, j = threadIdx.x;
    float acc = 0.f;
    for (int c = 0; c < NCHUNK; ++c)
        acc += partials[((size_t)b * NCHUNK + c) * H + j];
    pool_l[j] = acc * (1.f / NPG);
    __syncthreads();
    if (j < 2) {
        float o = fcb[j];
        for (int k = 0; k < H; ++k) o += pool_l[k] * fcw[k * 2 + j];
        out[b * 2 + j] = o;
    }
}

extern "C" void kernel_launch(void* const* d_in, const int* in_sizes, int n_in,
                              void* d_out, int out_size, void* d_ws, size_t ws_size,
                              hipStream_t stream) {
    (void)in_sizes; (void)n_in; (void)out_size; (void)ws_size;
    const float* x   = (const float*)d_in[0];
    // d_in[1] = batch_size (hardcoded 64)
    const float* c1w = (const float*)d_in[2];
    const float* c1b = (const float*)d_in[3];
    const float* c2w = (const float*)d_in[4];
    const float* c2b = (const float*)d_in[5];
    const float* g1w = (const float*)d_in[6];
    const float* g1b = (const float*)d_in[7];
    const float* g2w = (const float*)d_in[8];
    const float* g2b = (const float*)d_in[9];
    const float* fcw = (const float*)d_in[10];
    const float* fcb = (const float*)d_in[11];
    float* out = (float*)d_out;

    float* t1       = (float*)d_ws;                         // 16 MB
    float* nodes    = t1 + (size_t)BATCH * L1 * CF;         // 8 MB
    float* partials = nodes + (size_t)BATCH * NPG * CF;     // 512 KB
    unsigned short* w2f = (unsigned short*)(partials + (size_t)NCHUNKS_TOTAL * H);
    unsigned short* w1f = w2f + 4096;

    k_conv1<<<BATCH * L1 / 256 + 1, 256, 0, stream>>>(x, c1w, c1b, t1,
                                                      g1w, g2w, w1f, w2f);
    k_conv2<<<BATCH * NPG / 256, 256, 0, stream>>>(t1, c2w, c2b, nodes);
    k_gcn<<<GCN_BLOCKS, 256, 0, stream>>>(nodes, w1f, w2f, g1b, g2b, partials);
    k_final<<<BATCH, 64, 0, stream>>>(partials, fcw, fcb, out);
}

// Round 3
// 33.005 us; speedup vs baseline: 2.9694x; 1.3659x over previous
//
#include <hip/hip_runtime.h>

typedef __attribute__((ext_vector_type(8))) short short8_t;
typedef __attribute__((ext_vector_type(4))) float f32x4;

#define BATCH 64
#define L0 16384
#define L1 8192
#define NPG 4096
#define CF 8
#define H 64
#define CHUNK 128
#define NCHUNK 32
#define NCHUNKS_TOTAL (BATCH * NCHUNK)   // 2048

// ---- LDS arena byte offsets (phases alias dead regions) ----
#define A_WF1   0        // [4][64][8] short   = 4096 B   (GCN1 B-frags)
#define A_WF2   4096     // [4][2][64][8] short= 8192 B   (GCN2 B-frags)
#define A_WFC   12288    // [64][8] short      = 1024 B   (conv2 B-frag)
#define A_X     13312    // [536] f32          = 2144 B
#define A_T1    15488    // [274][8] ushort    = 4384 B  (bf16, post-pool1)
#define A_ND    19872    // [132][8] f32       = 4224 B
#define A_SA    24096    // [144][8] ushort    = 2304 B  (bf16 stencil(nodes))
#define A_H1    0        // [144][72] ushort   = 20736 B (aliases WF/X/T1/ND: all dead)
#define A_RED   26400    // [4][64] f32        = 1024 B
#define ARENA_BYTES 27424

__device__ __forceinline__ float disv(int p) {
    if (p < 0 || p >= NPG) return 0.f;
    if (p == 0 || p == NPG - 1) return 0.70710678118654752f;  // 1/sqrt(2)
    return 0.57735026918962576f;                              // 1/sqrt(3)
}

__device__ __forceinline__ unsigned short f2bf(float f) {
    unsigned u = __float_as_uint(f);
    u += 0x7FFFu + ((u >> 16) & 1u);     // RNE
    return (unsigned short)(u >> 16);
}

__device__ __forceinline__ float bf2f(unsigned short u) {
    return __uint_as_float(((unsigned)u) << 16);
}

// Fully fused: conv1+pool -> conv2(MFMA)+pool -> GCN1(MFMA) -> GCN2(MFMA) -> pool
// One block per 128-node chunk. 256 threads = 4 waves.
__global__ __launch_bounds__(256, 4) void k_fused(const float* __restrict__ x,
        const float* __restrict__ c1w, const float* __restrict__ c1b,
        const float* __restrict__ c2w, const float* __restrict__ c2b,
        const float* __restrict__ g1w, const float* __restrict__ g1b,
        const float* __restrict__ g2w, const float* __restrict__ g2b,
        float* __restrict__ partials) {
    __shared__ __align__(16) char arena[ARENA_BYTES];
    short*          wf1  = (short*)(arena + A_WF1);
    short*          wf2  = (short*)(arena + A_WF2);
    short*          wfc  = (short*)(arena + A_WFC);
    float*          x_l  = (float*)(arena + A_X);
    unsigned short* t1_l = (unsigned short*)(arena + A_T1);
    float*          nd_l = (float*)(arena + A_ND);
    unsigned short* sa_l = (unsigned short*)(arena + A_SA);
    unsigned short* h1_l = (unsigned short*)(arena + A_H1);
    float*          red  = (float*)(arena + A_RED);

    const int tid = threadIdx.x;
    const int wave = tid >> 6;
    const int l = tid & 63;
    const int m = l & 15, q = l >> 4;

    const int chunk = blockIdx.x;
    const int b = chunk >> 5, ch = chunk & 31;
    const int s = ch * CHUNK;

    // ---- phase 1: build weight fragments + stage x segment ----
    for (int e = tid; e < 4096; e += 256) {          // wf2[ct][ks][lane][i]
        int i = e & 7, lane = (e >> 3) & 63, ks = (e >> 9) & 1, ct = e >> 10;
        int k = ks * 32 + (lane >> 4) * 8 + i;
        int n = ct * 16 + (lane & 15);
        wf2[e] = f2bf(g2w[k * H + n]);
    }
    for (int e = tid; e < 2048; e += 256) {          // wf1[ct][lane][i]
        int i = e & 7, lane = (e >> 3) & 63, ct = e >> 9;
        int k = (lane >> 4) * 8 + i;
        int n = ct * 16 + (lane & 15);
        wf1[e] = (k < CF) ? f2bf(g1w[k * H + n]) : (short)0;
    }
    for (int e = tid; e < 512; e += 256) {           // wfc[lane][i]: B[k=q*8+i][n]
        int i = e & 7, lane = e >> 3;
        int qq = lane >> 4, n = lane & 15;
        wfc[e] = (n < CF && qq < 3) ? f2bf(c2w[(n * CF + i) * 3 + qq]) : (short)0;
    }
    {   // x cols [4s-11, 4s+522], zero outside [0, L0)
        const float* xb = x + (size_t)b * L0;
        for (int c = tid; c < 536; c += 256) {
            int col = 4 * s - 11 + c;
            x_l[c] = (col >= 0 && col < L0) ? xb[col] : 0.f;
        }
    }
    __syncthreads();

    // ---- phase 2: load frags to regs  ||  conv1+pool -> t1 (bf16) ----
    short8_t w1fr[4], w2fr[4][2], wcfr;
    float b1v[4], b2v[4];
    {
        const short8_t* v1 = (const short8_t*)wf1;
        const short8_t* v2 = (const short8_t*)wf2;
        #pragma unroll
        for (int ct = 0; ct < 4; ++ct) {
            w1fr[ct]    = v1[ct * 64 + l];
            w2fr[ct][0] = v2[(ct * 2 + 0) * 64 + l];
            w2fr[ct][1] = v2[(ct * 2 + 1) * 64 + l];
            b1v[ct] = g1b[ct * 16 + m];
            b2v[ct] = g2b[ct * 16 + m];
        }
        wcfr = ((const short8_t*)wfc)[l];
    }
    {
        int c = tid & 7;
        float wA = c1w[c * 3], wB = c1w[c * 3 + 1], wC = c1w[c * 3 + 2];
        float bb = c1b[c];
        for (int v = tid; v < 274 * 8; v += 256) {
            int t = v >> 3;
            int g = 2 * s - 5 + t;               // global t1 row
            unsigned short o = 0;
            if (t < 266 && g >= 0 && g < L1) {
                float a0 = x_l[2 * t], a1 = x_l[2 * t + 1];
                float a2 = x_l[2 * t + 2], a3 = x_l[2 * t + 3];
                float y0 = bb + wA * a0 + wB * a1 + wC * a2;
                float y1 = bb + wA * a1 + wB * a2 + wC * a3;
                o = f2bf(fmaxf(fmaxf(y0, y1), 0.f));
            }
            t1_l[v] = o;
        }
    }
    __syncthreads();

    // ---- phase 3: conv2 via MFMA (+bias+relu+pool) -> nodes f32 ----
    {
        const f32x4 z4 = {0.f, 0.f, 0.f, 0.f};
        float bb2 = (m < CF) ? c2b[m] : 0.f;
        for (int rt = wave; rt < 17; rt += 4) {
            short8_t a = {0, 0, 0, 0, 0, 0, 0, 0};
            if (q < 3) a = *(const short8_t*)&t1_l[(rt * 16 + m + q) * 8];
            f32x4 c = __builtin_amdgcn_mfma_f32_16x16x32_bf16(a, wcfr, z4, 0, 0, 0);
            if (m < CF) {
                int n0 = rt * 8 + q * 2;
                if (n0 < 132)
                    nd_l[n0 * 8 + m] = fmaxf(fmaxf(c[0], c[1]) + bb2, 0.f);
                if (n0 + 1 < 132)
                    nd_l[(n0 + 1) * 8 + m] = fmaxf(fmaxf(c[2], c[3]) + bb2, 0.f);
            }
        }
    }
    __syncthreads();

    // ---- phase 4: sstA = stencil(nodes), bf16 ----
    for (int v = tid; v < 144 * 8; v += 256) {
        int r = v >> 3, c = v & 7;
        unsigned short o = 0;
        if (r < 130) {
            int p = s - 1 + r;
            float dc = disv(p), dl = disv(p - 1), dr = disv(p + 1);
            o = f2bf(dc * (dc * nd_l[(r + 1) * 8 + c] + dl * nd_l[r * 8 + c]
                           + dr * nd_l[(r + 2) * 8 + c]));
        }
        sa_l[v] = o;
    }
    __syncthreads();

    // ---- phase 5: GCN1 MFMA -> h1 (bf16, stride 72) ----
    {
        const f32x4 z4 = {0.f, 0.f, 0.f, 0.f};
        for (int rt = wave; rt < 9; rt += 4) {
            short8_t a = *(const short8_t*)&sa_l[(rt * 16 + m) * 8];
            #pragma unroll
            for (int ct = 0; ct < 4; ++ct) {
                f32x4 c = __builtin_amdgcn_mfma_f32_16x16x32_bf16(a, w1fr[ct], z4, 0, 0, 0);
                #pragma unroll
                for (int i = 0; i < 4; ++i)
                    h1_l[(rt * 16 + q * 4 + i) * 72 + ct * 16 + m] =
                        f2bf(fmaxf(c[i] + b1v[ct], 0.f));
            }
        }
    }
    __syncthreads();

    // ---- phase 6: GCN2 MFMA (A2 = stencil(h1) built in regs) + pool ----
    float pool_acc[4] = {0.f, 0.f, 0.f, 0.f};
    {
        const f32x4 z4 = {0.f, 0.f, 0.f, 0.f};
        for (int rt = wave; rt < 8; rt += 4) {
            f32x4 accg[4] = {z4, z4, z4, z4};
            int r0 = rt * 16 + m;
            int p = s + r0;
            float dcp = disv(p), dlp = disv(p - 1), drp = disv(p + 1);
            float cl = dcp * dlp, cm = dcp * dcp, cr = dcp * drp;
            #pragma unroll
            for (int ks = 0; ks < 2; ++ks) {
                int koff = ks * 32 + q * 8;
                short8_t lo = *(const short8_t*)&h1_l[r0 * 72 + koff];
                short8_t mi = *(const short8_t*)&h1_l[(r0 + 1) * 72 + koff];
                short8_t hi = *(const short8_t*)&h1_l[(r0 + 2) * 72 + koff];
                short8_t a2;
                #pragma unroll
                for (int e = 0; e < 8; ++e)
                    a2[e] = (short)f2bf(cm * bf2f((unsigned short)mi[e])
                                      + cl * bf2f((unsigned short)lo[e])
                                      + cr * bf2f((unsigned short)hi[e]));
                #pragma unroll
                for (int ct = 0; ct < 4; ++ct)
                    accg[ct] = __builtin_amdgcn_mfma_f32_16x16x32_bf16(
                        a2, w2fr[ct][ks], accg[ct], 0, 0, 0);
            }
            #pragma unroll
            for (int ct = 0; ct < 4; ++ct)
                #pragma unroll
                for (int i = 0; i < 4; ++i)
                    pool_acc[ct] += fmaxf(accg[ct][i] + b2v[ct], 0.f);
        }
    }

    // ---- reduce q-groups + waves, write chunk partials ----
    #pragma unroll
    for (int ct = 0; ct < 4; ++ct) {
        float v = pool_acc[ct];
        v += __shfl_xor(v, 16);
        v += __shfl_xor(v, 32);
        if (q == 0) red[wave * 64 + ct * 16 + m] = v;
    }
    __syncthreads();
    if (tid < H) {
        partials[(size_t)chunk * H + tid] = red[tid] + red[64 + tid]
                                          + red[128 + tid] + red[192 + tid];
    }
}

// per-graph reduce over chunks + mean + fc
__global__ __launch_bounds__(64) void k_final(const float* __restrict__ partials,
        const float* __restrict__ fcw, const float* __restrict__ fcb,
        float* __restrict__ out) {
    __shared__ float pool_l[H];
    int b = blockIdx.x, j = threadIdx.x;
    float acc = 0.f;
    for (int c = 0; c < NCHUNK; ++c)
        acc += partials[((size_t)b * NCHUNK + c) * H + j];
    pool_l[j] = acc * (1.f / NPG);
    __syncthreads();
    if (j < 2) {
        float o = fcb[j];
        for (int k = 0; k < H; ++k) o += pool_l[k] * fcw[k * 2 + j];
        out[b * 2 + j] = o;
    }
}

extern "C" void kernel_launch(void* const* d_in, const int* in_sizes, int n_in,
                              void* d_out, int out_size, void* d_ws, size_t ws_size,
                              hipStream_t stream) {
    (void)in_sizes; (void)n_in; (void)out_size; (void)ws_size;
    const float* x   = (const float*)d_in[0];
    const float* c1w = (const float*)d_in[2];
    const float* c1b = (const float*)d_in[3];
    const float* c2w = (const float*)d_in[4];
    const float* c2b = (const float*)d_in[5];
    const float* g1w = (const float*)d_in[6];
    const float* g1b = (const float*)d_in[7];
    const float* g2w = (const float*)d_in[8];
    const float* g2b = (const float*)d_in[9];
    const float* fcw = (const float*)d_in[10];
    const float* fcb = (const float*)d_in[11];
    float* out = (float*)d_out;

    float* partials = (float*)d_ws;     // [2048][64] f32 = 512 KB

    k_fused<<<NCHUNKS_TOTAL, 256, 0, stream>>>(x, c1w, c1b, c2w, c2b,
                                               g1w, g1b, g2w, g2b, partials);
    k_final<<<BATCH, 64, 0, stream>>>(partials, fcw, fcb, out);
}

// Round 4
// 31.467 us; speedup vs baseline: 3.1146x; 1.0489x over previous
//
#include <hip/hip_runtime.h>

typedef __attribute__((ext_vector_type(8))) short short8_t;
typedef __attribute__((ext_vector_type(4))) float f32x4;

#define BATCH 64
#define L0 16384
#define L1 8192
#define NPG 4096
#define CF 8
#define H 64
#define CHUNK 128
#define NCHUNK 32
#define NCHUNKS_TOTAL (BATCH * NCHUNK)   // 2048

// ---- LDS arena byte offsets (phases alias dead regions) ----
// h1 [0,20736) overlaps x/t1/nd, all dead before phase 5 writes h1.
#define A_H1    0        // [144][72] ushort = 20736 B
#define A_X     0        // [536] f32        = 2144 B  (dead after phase 2)
#define A_T1    2144     // [274][8] ushort  = 4384 B  (dead after phase 3)
#define A_ND    6528     // [132][8] f32     = 4224 B  (dead after phase 4)
#define A_SA    20736    // [144][8] ushort  = 2304 B  (read in phase 5)
#define A_RED   23040    // [4][64] f32      = 1024 B
#define ARENA_BYTES 24064

__device__ __forceinline__ float disv(int p) {
    if (p < 0 || p >= NPG) return 0.f;
    if (p == 0 || p == NPG - 1) return 0.70710678118654752f;  // 1/sqrt(2)
    return 0.57735026918962576f;                              // 1/sqrt(3)
}

__device__ __forceinline__ unsigned short f2bf(float f) {
    unsigned u = __float_as_uint(f);
    u += 0x7FFFu + ((u >> 16) & 1u);     // RNE
    return (unsigned short)(u >> 16);
}

__device__ __forceinline__ float bf2f(unsigned short u) {
    return __uint_as_float(((unsigned)u) << 16);
}

// One-block prep: build bf16 MFMA B-fragments for W1 / W2 / conv2-W once.
__global__ __launch_bounds__(256) void k_prep(
        const float* __restrict__ g1w, const float* __restrict__ g2w,
        const float* __restrict__ c2w,
        unsigned short* __restrict__ w1f, unsigned short* __restrict__ w2f,
        unsigned short* __restrict__ wcf) {
    int tid = threadIdx.x;
    // B-frag layout for mfma_f32_16x16x32_bf16: lane holds B[k][n],
    // n = lane&15, k = (lane>>4)*8 + i, i = 0..7
    for (int e = tid; e < 4096; e += 256) {          // w2f[ct][ks][lane][i]
        int i = e & 7, lane = (e >> 3) & 63, ks = (e >> 9) & 1, ct = e >> 10;
        int k = ks * 32 + (lane >> 4) * 8 + i;
        int n = ct * 16 + (lane & 15);
        w2f[e] = f2bf(g2w[k * H + n]);
    }
    for (int e = tid; e < 2048; e += 256) {          // w1f[ct][lane][i]
        int i = e & 7, lane = (e >> 3) & 63, ct = e >> 9;
        int k = (lane >> 4) * 8 + i;
        int n = ct * 16 + (lane & 15);
        w1f[e] = (k < CF) ? f2bf(g1w[k * H + n]) : (unsigned short)0;
    }
    for (int e = tid; e < 512; e += 256) {           // wcf[lane][i]
        int i = e & 7, lane = e >> 3;
        int qq = lane >> 4, n = lane & 15;
        wcf[e] = (n < CF && qq < 3) ? f2bf(c2w[(n * CF + i) * 3 + qq])
                                    : (unsigned short)0;
    }
}

// Fully fused: conv1+pool -> conv2(MFMA)+pool -> GCN1(MFMA) -> GCN2(MFMA) -> pool
__global__ __launch_bounds__(256, 4) void k_fused(const float* __restrict__ x,
        const float* __restrict__ c1w, const float* __restrict__ c1b,
        const float* __restrict__ c2b,
        const unsigned short* __restrict__ w1f,
        const unsigned short* __restrict__ w2f,
        const unsigned short* __restrict__ wcf,
        const float* __restrict__ g1b, const float* __restrict__ g2b,
        float* __restrict__ partials) {
    __shared__ __align__(16) char arena[ARENA_BYTES];
    float*          x_l  = (float*)(arena + A_X);
    unsigned short* t1_l = (unsigned short*)(arena + A_T1);
    float*          nd_l = (float*)(arena + A_ND);
    unsigned short* sa_l = (unsigned short*)(arena + A_SA);
    unsigned short* h1_l = (unsigned short*)(arena + A_H1);
    float*          red  = (float*)(arena + A_RED);

    const int tid = threadIdx.x;
    const int wave = tid >> 6;
    const int l = tid & 63;
    const int m = l & 15, q = l >> 4;

    const int chunk = blockIdx.x;
    const int b = chunk >> 5, ch = chunk & 31;
    const int s = ch * CHUNK;

    // ---- load weight fragments from global (L2-resident, coalesced) ----
    short8_t w1fr[4], w2fr[4][2], wcfr;
    float b1v[4], b2v[4];
    {
        const short8_t* v1 = (const short8_t*)w1f;
        const short8_t* v2 = (const short8_t*)w2f;
        #pragma unroll
        for (int ct = 0; ct < 4; ++ct) {
            w1fr[ct]    = v1[ct * 64 + l];
            w2fr[ct][0] = v2[(ct * 2 + 0) * 64 + l];
            w2fr[ct][1] = v2[(ct * 2 + 1) * 64 + l];
            b1v[ct] = g1b[ct * 16 + m];
            b2v[ct] = g2b[ct * 16 + m];
        }
        wcfr = ((const short8_t*)wcf)[l];
    }

    // ---- phase 1: stage x segment [4s-11, 4s+524] ----
    {
        const float* xb = x + (size_t)b * L0;
        for (int c = tid; c < 536; c += 256) {
            int col = 4 * s - 11 + c;
            x_l[c] = (col >= 0 && col < L0) ? xb[col] : 0.f;
        }
    }
    __syncthreads();

    // ---- phase 2: conv1+pool -> t1 (bf16), 2 channels per thread ----
    {
        int c0 = (tid & 3) * 2;
        float wA0 = c1w[c0 * 3], wB0 = c1w[c0 * 3 + 1], wC0 = c1w[c0 * 3 + 2];
        float wA1 = c1w[c0 * 3 + 3], wB1 = c1w[c0 * 3 + 4], wC1 = c1w[c0 * 3 + 5];
        float bb0 = c1b[c0], bb1 = c1b[c0 + 1];
        for (int v = tid; v < 274 * 4; v += 256) {
            int t = v >> 2;
            int g = 2 * s - 5 + t;               // global t1 row
            unsigned o = 0;
            if (t < 266 && g >= 0 && g < L1) {
                float a0 = x_l[2 * t], a1 = x_l[2 * t + 1];
                float a2 = x_l[2 * t + 2], a3 = x_l[2 * t + 3];
                float y00 = bb0 + wA0 * a0 + wB0 * a1 + wC0 * a2;
                float y01 = bb0 + wA0 * a1 + wB0 * a2 + wC0 * a3;
                float y10 = bb1 + wA1 * a0 + wB1 * a1 + wC1 * a2;
                float y11 = bb1 + wA1 * a1 + wB1 * a2 + wC1 * a3;
                o = (unsigned)f2bf(fmaxf(fmaxf(y00, y01), 0.f))
                  | ((unsigned)f2bf(fmaxf(fmaxf(y10, y11), 0.f)) << 16);
            }
            *(unsigned*)&t1_l[t * 8 + c0] = o;
        }
    }
    __syncthreads();

    // ---- phase 3: conv2 via MFMA (+bias+relu+pool) -> nodes f32 ----
    {
        const f32x4 z4 = {0.f, 0.f, 0.f, 0.f};
        float bb2 = (m < CF) ? c2b[m] : 0.f;
        for (int rt = wave; rt < 17; rt += 4) {
            short8_t a = {0, 0, 0, 0, 0, 0, 0, 0};
            if (q < 3) a = *(const short8_t*)&t1_l[(rt * 16 + m + q) * 8];
            f32x4 c = __builtin_amdgcn_mfma_f32_16x16x32_bf16(a, wcfr, z4, 0, 0, 0);
            if (m < CF) {
                int n0 = rt * 8 + q * 2;
                if (n0 < 132)
                    nd_l[n0 * 8 + m] = fmaxf(fmaxf(c[0], c[1]) + bb2, 0.f);
                if (n0 + 1 < 132)
                    nd_l[(n0 + 1) * 8 + m] = fmaxf(fmaxf(c[2], c[3]) + bb2, 0.f);
            }
        }
    }
    __syncthreads();

    // ---- phase 4: sstA = stencil(nodes), bf16, 4 elems per thread ----
    for (int v = tid; v < 288; v += 256) {
        int r = v >> 1, half = v & 1;
        uint2 o = {0u, 0u};
        if (r < 130) {
            int p = s - 1 + r;
            float dc = disv(p), dl = disv(p - 1), dr = disv(p + 1);
            float4 lo = *(const float4*)&nd_l[r * 8 + half * 4];
            float4 mi = *(const float4*)&nd_l[(r + 1) * 8 + half * 4];
            float4 hi = *(const float4*)&nd_l[(r + 2) * 8 + half * 4];
            float o0 = dc * (dc * mi.x + dl * lo.x + dr * hi.x);
            float o1 = dc * (dc * mi.y + dl * lo.y + dr * hi.y);
            float o2 = dc * (dc * mi.z + dl * lo.z + dr * hi.z);
            float o3 = dc * (dc * mi.w + dl * lo.w + dr * hi.w);
            o.x = (unsigned)f2bf(o0) | ((unsigned)f2bf(o1) << 16);
            o.y = (unsigned)f2bf(o2) | ((unsigned)f2bf(o3) << 16);
        }
        *(uint2*)&sa_l[r * 8 + half * 4] = o;
    }
    __syncthreads();

    // ---- phase 5: GCN1 MFMA -> h1 (bf16, stride 72) ----
    {
        const f32x4 z4 = {0.f, 0.f, 0.f, 0.f};
        for (int rt = wave; rt < 9; rt += 4) {
            short8_t a = *(const short8_t*)&sa_l[(rt * 16 + m) * 8];
            #pragma unroll
            for (int ct = 0; ct < 4; ++ct) {
                f32x4 c = __builtin_amdgcn_mfma_f32_16x16x32_bf16(a, w1fr[ct], z4, 0, 0, 0);
                #pragma unroll
                for (int i = 0; i < 4; ++i)
                    h1_l[(rt * 16 + q * 4 + i) * 72 + ct * 16 + m] =
                        f2bf(fmaxf(c[i] + b1v[ct], 0.f));
            }
        }
    }
    __syncthreads();

    // ---- phase 6: GCN2 MFMA (A2 = stencil(h1) built in regs) + pool ----
    float pool_acc[4] = {0.f, 0.f, 0.f, 0.f};
    {
        const f32x4 z4 = {0.f, 0.f, 0.f, 0.f};
        for (int rt = wave; rt < 8; rt += 4) {
            f32x4 accg[4] = {z4, z4, z4, z4};
            int r0 = rt * 16 + m;
            int p = s + r0;
            float dcp = disv(p), dlp = disv(p - 1), drp = disv(p + 1);
            float cl = dcp * dlp, cm = dcp * dcp, cr = dcp * drp;
            #pragma unroll
            for (int ks = 0; ks < 2; ++ks) {
                int koff = ks * 32 + q * 8;
                short8_t lo = *(const short8_t*)&h1_l[r0 * 72 + koff];
                short8_t mi = *(const short8_t*)&h1_l[(r0 + 1) * 72 + koff];
                short8_t hi = *(const short8_t*)&h1_l[(r0 + 2) * 72 + koff];
                short8_t a2;
                #pragma unroll
                for (int e = 0; e < 8; ++e)
                    a2[e] = (short)f2bf(cm * bf2f((unsigned short)mi[e])
                                      + cl * bf2f((unsigned short)lo[e])
                                      + cr * bf2f((unsigned short)hi[e]));
                #pragma unroll
                for (int ct = 0; ct < 4; ++ct)
                    accg[ct] = __builtin_amdgcn_mfma_f32_16x16x32_bf16(
                        a2, w2fr[ct][ks], accg[ct], 0, 0, 0);
            }
            #pragma unroll
            for (int ct = 0; ct < 4; ++ct)
                #pragma unroll
                for (int i = 0; i < 4; ++i)
                    pool_acc[ct] += fmaxf(accg[ct][i] + b2v[ct], 0.f);
        }
    }

    // ---- reduce q-groups + waves, write chunk partials ----
    #pragma unroll
    for (int ct = 0; ct < 4; ++ct) {
        float v = pool_acc[ct];
        v += __shfl_xor(v, 16);
        v += __shfl_xor(v, 32);
        if (q == 0) red[wave * 64 + ct * 16 + m] = v;
    }
    __syncthreads();
    if (tid < H) {
        partials[(size_t)chunk * H + tid] = red[tid] + red[64 + tid]
                                          + red[128 + tid] + red[192 + tid];
    }
}

// per-graph reduce over chunks + mean + fc
__global__ __launch_bounds__(64) void k_final(const float* __restrict__ partials,
        const float* __restrict__ fcw, const float* __restrict__ fcb,
        float* __restrict__ out) {
    __shared__ float pool_l[H];
    int b = blockIdx.x, j = threadIdx.x;
    float acc = 0.f;
    for (int c = 0; c < NCHUNK; ++c)
        acc += partials[((size_t)b * NCHUNK + c) * H + j];
    pool_l[j] = acc * (1.f / NPG);
    __syncthreads();
    if (j < 2) {
        float o = fcb[j];
        for (int k = 0; k < H; ++k) o += pool_l[k] * fcw[k * 2 + j];
        out[b * 2 + j] = o;
    }
}

extern "C" void kernel_launch(void* const* d_in, const int* in_sizes, int n_in,
                              void* d_out, int out_size, void* d_ws, size_t ws_size,
                              hipStream_t stream) {
    (void)in_sizes; (void)n_in; (void)out_size; (void)ws_size;
    const float* x   = (const float*)d_in[0];
    const float* c1w = (const float*)d_in[2];
    const float* c1b = (const float*)d_in[3];
    const float* c2w = (const float*)d_in[4];
    const float* c2b = (const float*)d_in[5];
    const float* g1w = (const float*)d_in[6];
    const float* g1b = (const float*)d_in[7];
    const float* g2w = (const float*)d_in[8];
    const float* g2b = (const float*)d_in[9];
    const float* fcw = (const float*)d_in[10];
    const float* fcb = (const float*)d_in[11];
    float* out = (float*)d_out;

    float* partials = (float*)d_ws;                          // 512 KB
    unsigned short* w2f = (unsigned short*)(partials + (size_t)NCHUNKS_TOTAL * H);
    unsigned short* w1f = w2f + 4096;
    unsigned short* wcf = w1f + 2048;

    k_prep<<<1, 256, 0, stream>>>(g1w, g2w, c2w, w1f, w2f, wcf);
    k_fused<<<NCHUNKS_TOTAL, 256, 0, stream>>>(x, c1w, c1b, c2b,
                                               w1f, w2f, wcf, g1b, g2b, partials);
    k_final<<<BATCH, 64, 0, stream>>>(partials, fcw, fcb, out);
}